// Round 11
// baseline (866.480 us; speedup 1.0000x reference)
//
#include <hip/hip_runtime.h>

// ---------------------------------------------------------------------------
// SRU LM: emb-gather -> SRU(512->1024,k4) -> 4x SRU(1024,k3) -> SRU(1024->512,k4)
//         -> logits = h @ emb^T + bias
// L=128 B=32 E=512 D=1024 V=32000 MID=4
// Round 11 = round 10 + (a) GEMM on v_mfma_f32_32x32x16_bf16 (16 MFMA/K-step
// instead of 32; ~15% faster matrix pipe, half the issue slots) and
// (b) 8-deep scan pipeline (16 outstanding loads cover ~500cy L3 latency).
// GEMM: 128x128 tile, 256 thr, single-buffered 32KiB LDS, multi-block/CU;
// XCD-bijective swizzle, m-fastest tile order; write-combined epilogue.
// U bf16 in d_out (logits overwrite at end).
// ---------------------------------------------------------------------------

typedef __attribute__((ext_vector_type(8))) __bf16 bf16x8;
typedef __attribute__((ext_vector_type(16))) float f32x16;
typedef __attribute__((ext_vector_type(4))) float float4v;
typedef __attribute__((ext_vector_type(4))) unsigned short u16x4;

__device__ __forceinline__ unsigned short f2bf(float f) {
  unsigned int u = __builtin_bit_cast(unsigned int, f);
  u += 0x7fffu + ((u >> 16) & 1u);          // RNE
  return (unsigned short)(u >> 16);
}
__device__ __forceinline__ float bf2f(unsigned short v) {
  unsigned int u = ((unsigned int)v) << 16;
  return __builtin_bit_cast(float, u);
}

#define GLDS16(SRC, DST)                                                      \
  __builtin_amdgcn_global_load_lds(                                           \
      (__attribute__((address_space(1))) void*)(SRC),                         \
      (__attribute__((address_space(3))) void*)(DST), 16, 0, 0)

// ---------------------------------------------------------------------------
// 128x128-tile GEMM, 32x32x16 MFMA.  C[m][n] = sum_k A[m][k]*B[n][k].
// A:(M,K) bf16, B:(N,K) bf16.  BF16OUT: C bf16 (no bias) else C fp32 (+bias).
// 256 thr = 4 waves (2x2), 64x64 out/wave = 2x2 frags of 32x32 (f32x16 acc).
// LDS slot-swizzle: LDS[row][slot] = global 16B-slot (slot ^ (row&7)).
// A/B frag: row = base + (lane&31); k-slot = kk*2 + (lane>>5)  (K=16/inst,
// kk=0..3 over BK=64); quarter-wave bank aliasing is 2-way (free).
// C/D frag (measured m74/m101): col = lane&31, row=(r&3)+8*(r>>2)+4*(lane>>5).
// Tile order m-fastest: consecutive wg on an XCD share B n-panel (L2).
// ---------------------------------------------------------------------------
template <bool BF16OUT>
__global__ __launch_bounds__(256, 4)
void gemm128(const unsigned short* __restrict__ A,
             const unsigned short* __restrict__ B,
             void* __restrict__ Cv, const float* __restrict__ bias,
             int M, int N, int K, int tiles_m) {
  __shared__ __align__(16) unsigned short As[128 * 64];
  __shared__ __align__(16) unsigned short Bs[128 * 64];

  const int tid  = threadIdx.x;
  const int lane = tid & 63;
  const int wave = tid >> 6;
  const int wm = wave >> 1, wn = wave & 1;

  // bijective XCD swizzle (nwg % 8 == 0 for all our grids)
  const int nwg  = gridDim.x;
  const int orig = blockIdx.x;
  const int wg   = (orig & 7) * (nwg >> 3) + (orig >> 3);
  const int by = wg % tiles_m, bx = wg / tiles_m;   // m-fastest
  const int m0 = by * 128, n0 = bx * 128;

  const int srow  = lane >> 3;
  const int sslot = (lane & 7) ^ srow;
  const int cl = lane & 31;            // frag row / C col
  const int hi = lane >> 5;

  f32x16 acc[2][2] = {};               // 64 VGPR

  const int ksteps = K >> 6;
  for (int ks = 0; ks < ksteps; ++ks) {
    const int k0 = ks << 6;
#pragma unroll
    for (int j = 0; j < 4; ++j) {
      const int rbase = (j * 4 + wave) * 8;          // wave-uniform
      const int r = rbase + srow;
      const unsigned short* sa = A + (size_t)(m0 + r) * K + k0 + sslot * 8;
      const unsigned short* sb = B + (size_t)(n0 + r) * K + k0 + sslot * 8;
      GLDS16(sa, &As[rbase * 64]);
      GLDS16(sb, &Bs[rbase * 64]);
    }
    __syncthreads();
#pragma unroll
    for (int kk = 0; kk < 4; ++kk) {
      const int slot = (kk * 2 + hi) ^ (lane & 7);
      const bf16x8 a0 = *(const bf16x8*)&As[(wm * 64 +  0 + cl) * 64 + slot * 8];
      const bf16x8 a1 = *(const bf16x8*)&As[(wm * 64 + 32 + cl) * 64 + slot * 8];
      const bf16x8 b0 = *(const bf16x8*)&Bs[(wn * 64 +  0 + cl) * 64 + slot * 8];
      const bf16x8 b1 = *(const bf16x8*)&Bs[(wn * 64 + 32 + cl) * 64 + slot * 8];
      acc[0][0] = __builtin_amdgcn_mfma_f32_32x32x16_bf16(a0, b0, acc[0][0], 0, 0, 0);
      acc[0][1] = __builtin_amdgcn_mfma_f32_32x32x16_bf16(a0, b1, acc[0][1], 0, 0, 0);
      acc[1][0] = __builtin_amdgcn_mfma_f32_32x32x16_bf16(a1, b0, acc[1][0], 0, 0, 0);
      acc[1][1] = __builtin_amdgcn_mfma_f32_32x32x16_bf16(a1, b1, acc[1][1], 0, 0, 0);
    }
    __syncthreads();
  }

  // epilogue, write-combined: per (fa,r), the fb=0/1 stores are adjacent
  // col segments of the same rows -> full 128B lines.
  if constexpr (BF16OUT) {
    unsigned short* C = (unsigned short*)Cv;
#pragma unroll
    for (int fa = 0; fa < 2; ++fa)
#pragma unroll
      for (int r = 0; r < 16; ++r) {
        const int row = m0 + wm * 64 + fa * 32 + (r & 3) + 8 * (r >> 2) + 4 * hi;
        unsigned short* Crow = C + (size_t)row * N + n0 + wn * 64 + cl;
        Crow[0]  = f2bf(acc[fa][0][r]);
        Crow[32] = f2bf(acc[fa][1][r]);
      }
  } else {
    float* C = (float*)Cv;
    float bv0 = bias ? bias[n0 + wn * 64 + cl] : 0.0f;
    float bv1 = bias ? bias[n0 + wn * 64 + 32 + cl] : 0.0f;
#pragma unroll
    for (int fa = 0; fa < 2; ++fa)
#pragma unroll
      for (int r = 0; r < 16; ++r) {
        const int row = m0 + wm * 64 + fa * 32 + (r & 3) + 8 * (r >> 2) + 4 * hi;
        float* Crow = C + (size_t)row * N + n0 + wn * 64 + cl;
        Crow[0]  = acc[fa][0][r] + bv0;
        Crow[32] = acc[fa][1][r] + bv1;
      }
  }
}

// ---------------------------------------------------------------------------
// SRU scan, 8-deep software-pipelined.  One thread per (b,d) chain, L=128.
// U is bf16 (L,B,k*n_out).  hw = U[...,3n:] if K4 else bf16 hin.
// ---------------------------------------------------------------------------
template <bool K4>
__global__ void scan_k(const unsigned short* __restrict__ U,
                       const float* __restrict__ bias,
                       const float* __restrict__ c0,
                       const unsigned short* __restrict__ hin,
                       unsigned short* __restrict__ hout, int n_out) {
  const int idx = blockIdx.x * 64 + threadIdx.x;     // 0 .. 32*n_out
  const int b = idx / n_out;
  const int d = idx - b * n_out;
  const float biasf = bias[d];
  const float biasr = bias[n_out + d];
  float c = c0[idx];
  const int rowlen = (K4 ? 4 : 3) * n_out;
  const unsigned short* Up = U + (size_t)b * rowlen + d;
  const size_t lstride = (size_t)32 * rowlen;
  const unsigned short* hp = hin + (size_t)b * n_out + d;
  unsigned short* op = hout + (size_t)b * n_out + d;
  const size_t hstride = (size_t)32 * n_out;

  float xt0, fr0, rr0, hw0, xt1, fr1, rr1, hw1;
  float xt2, fr2, rr2, hw2, xt3, fr3, rr3, hw3;
  float xt4, fr4, rr4, hw4, xt5, fr5, rr5, hw5;
  float xt6, fr6, rr6, hw6, xt7, fr7, rr7, hw7;

#define SRU_LOAD(S)                                                           \
  do {                                                                        \
    xt##S = bf2f(Up[0]);                                                      \
    fr##S = bf2f(Up[n_out]);                                                  \
    rr##S = bf2f(Up[2 * n_out]);                                              \
    hw##S = K4 ? bf2f(Up[3 * n_out]) : bf2f(*hp);                             \
    Up += lstride;                                                            \
    hp += hstride;                                                            \
  } while (0)

#define SRU_STEP(S)                                                           \
  do {                                                                        \
    const float f = 1.0f / (1.0f + __expf(-(fr##S + biasf)));                 \
    const float r = 1.0f / (1.0f + __expf(-(rr##S + biasr)));                 \
    c = f * c + (1.0f - f) * xt##S;                                           \
    const float e2 = __expf(2.0f * c);                                        \
    const float g = 1.0f - 2.0f / (e2 + 1.0f);                                \
    *op = f2bf(r * g + (1.0f - r) * hw##S);                                   \
    op += hstride;                                                            \
  } while (0)

  SRU_LOAD(0); SRU_LOAD(1); SRU_LOAD(2); SRU_LOAD(3);   // l = 0..7
  SRU_LOAD(4); SRU_LOAD(5); SRU_LOAD(6); SRU_LOAD(7);
  for (int l = 0; l < 120; l += 8) {                    // l = 0,8,...,112
    SRU_STEP(0); SRU_LOAD(0);                           // load l+8
    SRU_STEP(1); SRU_LOAD(1);
    SRU_STEP(2); SRU_LOAD(2);
    SRU_STEP(3); SRU_LOAD(3);
    SRU_STEP(4); SRU_LOAD(4);
    SRU_STEP(5); SRU_LOAD(5);
    SRU_STEP(6); SRU_LOAD(6);
    SRU_STEP(7); SRU_LOAD(7);
  }
  SRU_STEP(0); SRU_STEP(1); SRU_STEP(2); SRU_STEP(3);   // l = 120..127
  SRU_STEP(4); SRU_STEP(5); SRU_STEP(6); SRU_STEP(7);
#undef SRU_LOAD
#undef SRU_STEP
}

// ---------------------------------------------------------------------------
// Fused prep: emb->bf16 cvt, token gather, all 6 weight transposes (64x64
// tiles -> 128B-per-instruction output rows).  256 thr/block.
// ---------------------------------------------------------------------------
__device__ __forceinline__ void transpose_tile64(const float* __restrict__ W,
                                                 unsigned short* __restrict__ Wt,
                                                 int K, int N, int bx, int by,
                                                 int tid) {
  __shared__ float tile[64][65];
  const int n0 = bx * 64, k0 = by * 64;
  const int tx = tid & 63, ty = tid >> 6;   // (64,4)
#pragma unroll
  for (int i = 0; i < 64; i += 4)
    tile[ty + i][tx] = W[(size_t)(k0 + ty + i) * N + n0 + tx];
  __syncthreads();
#pragma unroll
  for (int i = 0; i < 64; i += 4)
    Wt[(size_t)(n0 + ty + i) * K + k0 + tx] = f2bf(tile[tx][ty + i]);
}

__global__ void prep_k(const int* __restrict__ x, const float* __restrict__ emb,
                       const float* __restrict__ W1, const float* __restrict__ W2,
                       const float* __restrict__ W3,
                       unsigned short* __restrict__ embbf,
                       unsigned short* __restrict__ h0,
                       unsigned short* __restrict__ W1t,
                       unsigned short* __restrict__ W2t,
                       unsigned short* __restrict__ W3t) {
  const int blk = blockIdx.x;
  const int tid = threadIdx.x;
  if (blk < 16000) {                                   // cvt emb -> bf16
    const int i = blk * 256 + tid;
    const float4v v = ((const float4v*)emb)[i];
    u16x4 o;
    o.x = f2bf(v.x); o.y = f2bf(v.y); o.z = f2bf(v.z); o.w = f2bf(v.w);
    ((u16x4*)embbf)[i] = o;
  } else if (blk < 24192) {                            // embed gather
    const int i = (blk - 16000) * 256 + tid;           // 0..2097151
    const int row = i >> 9, e = i & 511;
    const int tok = x[row];
    h0[i] = f2bf(emb[((size_t)tok << 9) + e]);
  } else if (blk < 24704) {                            // W1: K=512 N=4096
    const int r = blk - 24192;                         // 64 x 8
    transpose_tile64(W1, W1t, 512, 4096, r & 63, r >> 6, tid);
  } else if (blk < 27776) {                            // W2[i]: K=1024 N=3072
    const int r = blk - 24704;
    const int i = r / 768, rr = r - i * 768;           // 48 x 16 per layer
    transpose_tile64(W2 + (size_t)i * 3145728, W2t + (size_t)i * 3145728,
                     1024, 3072, rr % 48, rr / 48, tid);
  } else {                                             // W3: K=1024 N=2048
    const int r = blk - 27776;                         // 32 x 16
    transpose_tile64(W3, W3t, 1024, 2048, r & 31, r >> 5, tid);
  }
}

extern "C" void kernel_launch(void* const* d_in, const int* in_sizes, int n_in,
                              void* d_out, int out_size, void* d_ws, size_t ws_size,
                              hipStream_t stream) {
  (void)in_sizes; (void)n_in; (void)out_size; (void)ws_size;
  const int*   x     = (const int*)d_in[0];
  const float* c1    = (const float*)d_in[1];
  const float* c2    = (const float*)d_in[2];
  const float* c3    = (const float*)d_in[3];
  const float* emb   = (const float*)d_in[4];
  const float* obias = (const float*)d_in[5];
  const float* W1    = (const float*)d_in[6];
  const float* b1    = (const float*)d_in[7];
  const float* W2    = (const float*)d_in[8];
  const float* b2    = (const float*)d_in[9];
  const float* W3    = (const float*)d_in[10];
  const float* b3    = (const float*)d_in[11];

  char* ws = (char*)d_ws;
  unsigned short* hbfA  = (unsigned short*)ws;                  //  8,388,608 B
  unsigned short* hbfB  = (unsigned short*)(ws + 8388608);      //  8,388,608 B
  unsigned short* embbf = (unsigned short*)(ws + 16777216);     // 32,768,000 B
  unsigned short* W1t   = (unsigned short*)(ws + 49545216);     //  4,194,304 B
  unsigned short* W2t   = (unsigned short*)(ws + 53739520);     // 25,165,824 B
  unsigned short* W3t   = (unsigned short*)(ws + 78905344);     //  4,194,304 B
  unsigned short* U = (unsigned short*)d_out;  // bf16 U scratch (<=34MB) in
                                               // d_out; logits overwrite it.

  // all input prep in one launch (cvt, gather, 6 transposes — independent)
  prep_k<<<28288, 256, 0, stream>>>(x, emb, W1, W2, W3, embbf, hbfA,
                                    W1t, W2t, W3t);

  // ---- layer 1: (512 -> 1024, k=4): 32x32 = 1024 tiles ----
  gemm128<true><<<1024, 256, 0, stream>>>(hbfA, W1t, U, nullptr,
                                          4096, 4096, 512, 32);
  scan_k<true><<<512, 64, 0, stream>>>(U, b1, c1, hbfB, hbfB, 1024);

  // ---- mid layers: 4x (1024 -> 1024, k=3): 32x24 = 768 tiles ----
  const unsigned short* hin = hbfB;
  unsigned short* hout = hbfA;
  for (int i = 0; i < 4; ++i) {
    gemm128<true><<<768, 256, 0, stream>>>(hin, W2t + (size_t)i * 3145728, U,
                                           nullptr, 4096, 3072, 1024, 32);
    scan_k<false><<<512, 64, 0, stream>>>(U, b2 + i * 2048, c2 + (size_t)i * 32768,
                                          hin, hout, 1024);
    const unsigned short* t = hin; hin = hout; hout = (unsigned short*)t;
  }

  // ---- final SRU: (1024 -> 512, k=4): 32x16 = 512 tiles ----
  gemm128<true><<<512, 256, 0, stream>>>(hin, W3t, U, nullptr,
                                         4096, 2048, 1024, 32);
  scan_k<true><<<256, 64, 0, stream>>>(U, b3, c3, hout, hout, 512);

  // ---- logits: (4096 x 32000): 32x250 = 8000 tiles, fp32 + bias ----
  gemm128<false><<<8000, 256, 0, stream>>>(hout, embbf, (float*)d_out, obias,
                                           4096, 32000, 512, 32);
}

// Round 12
// 612.037 us; speedup vs baseline: 1.4157x; 1.4157x over previous
//
#include <hip/hip_runtime.h>

// ---------------------------------------------------------------------------
// SRU LM: emb-gather -> SRU(512->1024,k4) -> 4x SRU(1024,k3) -> SRU(1024->512,k4)
//         -> logits = h @ emb^T + bias
// L=128 B=32 E=512 D=1024 V=32000 MID=4
// Round 12 = round 10 (best, 615us) + embedding gather fused into L1 GEMM's
// A-staging (per-lane global_load_lds source = embbf[x[row]]; tokens cached
// in LDS).  Round-11's 32x32 MFMA + 8-deep scan REVERTED (+251us regression).
// GEMM: 128x128 tile (m97 structure), 16x16x32 MFMA, 256 thr, single-buffered
// 32KiB LDS, ~4 blocks/CU; XCD-bijective swizzle, m-fastest tile order;
// write-combined epilogue.  Scans: 4-deep pipelined, bf16 U.
// U bf16 scratch in d_out (logits overwrite at end).
// ---------------------------------------------------------------------------

typedef __attribute__((ext_vector_type(8))) __bf16 bf16x8;
typedef __attribute__((ext_vector_type(4))) float f32x4;
typedef __attribute__((ext_vector_type(4))) float float4v;
typedef __attribute__((ext_vector_type(4))) unsigned short u16x4;

__device__ __forceinline__ unsigned short f2bf(float f) {
  unsigned int u = __builtin_bit_cast(unsigned int, f);
  u += 0x7fffu + ((u >> 16) & 1u);          // RNE
  return (unsigned short)(u >> 16);
}
__device__ __forceinline__ float bf2f(unsigned short v) {
  unsigned int u = ((unsigned int)v) << 16;
  return __builtin_bit_cast(float, u);
}

#define GLDS16(SRC, DST)                                                      \
  __builtin_amdgcn_global_load_lds(                                           \
      (__attribute__((address_space(1))) void*)(SRC),                         \
      (__attribute__((address_space(3))) void*)(DST), 16, 0, 0)

// ---------------------------------------------------------------------------
// 128x128-tile GEMM (m97 structure).  C[m][n] = sum_k A[m][k]*B[n][k].
// A:(M,K) bf16, B:(N,K) bf16.  BF16OUT: C bf16 (no bias) else C fp32 (+bias).
// GATHER: A-row r sourced from A + x[m0+r]*K (token gather; A=embbf, K=512).
// M%128==0, N%128==0, K%64==0, grid%8==0.  256 thr = 4 waves (2x2),
// 64x64 out/wave (4x4 frags).  Single-buffered BK=64.
// LDS slot-swizzle: LDS[row][slot] = global 16B-slot (slot ^ (row&7)).
// Tile order m-fastest: consecutive wg on an XCD share B n-panel (L2).
// ---------------------------------------------------------------------------
template <bool BF16OUT, bool GATHER>
__global__ __launch_bounds__(256, 4)
void gemm128(const unsigned short* __restrict__ A,
             const unsigned short* __restrict__ B,
             void* __restrict__ Cv, const float* __restrict__ bias,
             const int* __restrict__ xrow,
             int M, int N, int K, int tiles_m) {
  __shared__ __align__(16) unsigned short As[128 * 64];
  __shared__ __align__(16) unsigned short Bs[128 * 64];
  __shared__ int xs[128];

  const int tid  = threadIdx.x;
  const int lane = tid & 63;
  const int wave = tid >> 6;
  const int wm = wave >> 1, wn = wave & 1;

  // bijective XCD swizzle (nwg % 8 == 0 for all our grids)
  const int nwg  = gridDim.x;
  const int orig = blockIdx.x;
  const int wg   = (orig & 7) * (nwg >> 3) + (orig >> 3);
  const int by = wg % tiles_m, bx = wg / tiles_m;   // m-fastest
  const int m0 = by * 128, n0 = bx * 128;

  if constexpr (GATHER) {
    if (tid < 128) xs[tid] = xrow[m0 + tid];
    __syncthreads();
  }

  const int srow  = lane >> 3;
  const int sslot = (lane & 7) ^ srow;
  const int fr = lane & 15;
  const int s0 = (lane >> 4) ^ (lane & 7);
  const int lg = lane >> 4;

  f32x4 acc[4][4] = {};

  const int ksteps = K >> 6;
  for (int ks = 0; ks < ksteps; ++ks) {
    const int k0 = ks << 6;
#pragma unroll
    for (int j = 0; j < 4; ++j) {
      const int rbase = (j * 4 + wave) * 8;          // wave-uniform
      const int r = rbase + srow;
      const unsigned short* sa;
      if constexpr (GATHER)
        sa = A + (size_t)xs[r] * K + k0 + sslot * 8;
      else
        sa = A + (size_t)(m0 + r) * K + k0 + sslot * 8;
      const unsigned short* sb = B + (size_t)(n0 + r) * K + k0 + sslot * 8;
      GLDS16(sa, &As[rbase * 64]);
      GLDS16(sb, &Bs[rbase * 64]);
    }
    __syncthreads();
#pragma unroll
    for (int kk = 0; kk < 2; ++kk) {
      const int slot = s0 ^ (kk << 2);
      bf16x8 a[4], b[4];
#pragma unroll
      for (int m = 0; m < 4; ++m)
        a[m] = *(const bf16x8*)&As[(wm * 64 + m * 16 + fr) * 64 + slot * 8];
#pragma unroll
      for (int n = 0; n < 4; ++n)
        b[n] = *(const bf16x8*)&Bs[(wn * 64 + n * 16 + fr) * 64 + slot * 8];
#pragma unroll
      for (int m = 0; m < 4; ++m)
#pragma unroll
        for (int n = 0; n < 4; ++n)
          acc[m][n] = __builtin_amdgcn_mfma_f32_16x16x32_bf16(a[m], b[n],
                                                              acc[m][n], 0, 0, 0);
    }
    __syncthreads();
  }

  // epilogue, write-combined order (m,r outer / n inner — round-8 lesson):
  // fp32: 4 x 64B segments/row back-to-back; bf16: 4 x 32B segs = 128B line.
  if constexpr (BF16OUT) {
    unsigned short* C = (unsigned short*)Cv;
#pragma unroll
    for (int m = 0; m < 4; ++m) {
      const int row = m0 + wm * 64 + m * 16 + lg * 4;
#pragma unroll
      for (int r = 0; r < 4; ++r) {
        unsigned short* Crow = C + (size_t)(row + r) * N + n0 + wn * 64 + fr;
#pragma unroll
        for (int n = 0; n < 4; ++n)
          Crow[n * 16] = f2bf(acc[m][n][r]);
      }
    }
  } else {
    float* C = (float*)Cv;
    float bv[4];
#pragma unroll
    for (int n = 0; n < 4; ++n)
      bv[n] = bias ? bias[n0 + wn * 64 + n * 16 + fr] : 0.0f;
#pragma unroll
    for (int m = 0; m < 4; ++m) {
      const int row = m0 + wm * 64 + m * 16 + lg * 4;
#pragma unroll
      for (int r = 0; r < 4; ++r) {
        float* Crow = C + (size_t)(row + r) * N + n0 + wn * 64 + fr;
#pragma unroll
        for (int n = 0; n < 4; ++n)
          Crow[n * 16] = acc[m][n][r] + bv[n];
      }
    }
  }
}

// ---------------------------------------------------------------------------
// SRU scan, 4-deep software-pipelined.  One thread per (b,d) chain, L=128.
// U is bf16 (L,B,k*n_out).  hw = U[...,3n:] if K4 else bf16 hin.
// ---------------------------------------------------------------------------
template <bool K4>
__global__ void scan_k(const unsigned short* __restrict__ U,
                       const float* __restrict__ bias,
                       const float* __restrict__ c0,
                       const unsigned short* __restrict__ hin,
                       unsigned short* __restrict__ hout, int n_out) {
  const int idx = blockIdx.x * 64 + threadIdx.x;     // 0 .. 32*n_out
  const int b = idx / n_out;
  const int d = idx - b * n_out;
  const float biasf = bias[d];
  const float biasr = bias[n_out + d];
  float c = c0[idx];
  const int rowlen = (K4 ? 4 : 3) * n_out;
  const unsigned short* Up = U + (size_t)b * rowlen + d;
  const size_t lstride = (size_t)32 * rowlen;
  const unsigned short* hp = hin + (size_t)b * n_out + d;
  unsigned short* op = hout + (size_t)b * n_out + d;
  const size_t hstride = (size_t)32 * n_out;

  float xt0, fr0, rr0, hw0, xt1, fr1, rr1, hw1;
  float xt2, fr2, rr2, hw2, xt3, fr3, rr3, hw3;

#define SRU_LOAD(S)                                                           \
  do {                                                                        \
    xt##S = bf2f(Up[0]);                                                      \
    fr##S = bf2f(Up[n_out]);                                                  \
    rr##S = bf2f(Up[2 * n_out]);                                              \
    hw##S = K4 ? bf2f(Up[3 * n_out]) : bf2f(*hp);                             \
    Up += lstride;                                                            \
    hp += hstride;                                                            \
  } while (0)

#define SRU_STEP(S)                                                           \
  do {                                                                        \
    const float f = 1.0f / (1.0f + __expf(-(fr##S + biasf)));                 \
    const float r = 1.0f / (1.0f + __expf(-(rr##S + biasr)));                 \
    c = f * c + (1.0f - f) * xt##S;                                           \
    const float e2 = __expf(2.0f * c);                                        \
    const float g = 1.0f - 2.0f / (e2 + 1.0f);                                \
    *op = f2bf(r * g + (1.0f - r) * hw##S);                                   \
    op += hstride;                                                            \
  } while (0)

  SRU_LOAD(0); SRU_LOAD(1); SRU_LOAD(2); SRU_LOAD(3);   // l = 0..3
  for (int l = 0; l < 124; l += 4) {                    // l = 0,4,...,120
    SRU_STEP(0); SRU_LOAD(0);                           // load l+4
    SRU_STEP(1); SRU_LOAD(1);
    SRU_STEP(2); SRU_LOAD(2);
    SRU_STEP(3); SRU_LOAD(3);
  }
  SRU_STEP(0); SRU_STEP(1); SRU_STEP(2); SRU_STEP(3);   // l = 124..127
#undef SRU_LOAD
#undef SRU_STEP
}

// ---------------------------------------------------------------------------
// Fused prep: emb->bf16 cvt + all 6 weight transposes (64x64 tiles ->
// 128B-per-instruction output rows).  256 thr/block.  (Token gather now
// lives inside the L1 GEMM.)
//   [0,16000)       cvt   emb (16,384,000 f32 -> bf16), 4/thread
//   [16000,16512)   T W1  (512 x 4096)   -> W1t : 64x8   = 512 tiles
//   [16512,19584)   T W2[i] (1024x3072)  -> W2t : 48x16x4= 3072 tiles
//   [19584,20096)   T W3  (1024 x 2048)  -> W3t : 32x16  = 512 tiles
// ---------------------------------------------------------------------------
__device__ __forceinline__ void transpose_tile64(const float* __restrict__ W,
                                                 unsigned short* __restrict__ Wt,
                                                 int K, int N, int bx, int by,
                                                 int tid) {
  __shared__ float tile[64][65];
  const int n0 = bx * 64, k0 = by * 64;
  const int tx = tid & 63, ty = tid >> 6;   // (64,4)
#pragma unroll
  for (int i = 0; i < 64; i += 4)
    tile[ty + i][tx] = W[(size_t)(k0 + ty + i) * N + n0 + tx];
  __syncthreads();
#pragma unroll
  for (int i = 0; i < 64; i += 4)
    Wt[(size_t)(n0 + ty + i) * K + k0 + tx] = f2bf(tile[tx][ty + i]);
}

__global__ void prep_k(const float* __restrict__ emb,
                       const float* __restrict__ W1,
                       const float* __restrict__ W2,
                       const float* __restrict__ W3,
                       unsigned short* __restrict__ embbf,
                       unsigned short* __restrict__ W1t,
                       unsigned short* __restrict__ W2t,
                       unsigned short* __restrict__ W3t) {
  const int blk = blockIdx.x;
  const int tid = threadIdx.x;
  if (blk < 16000) {                                   // cvt emb -> bf16
    const int i = blk * 256 + tid;
    const float4v v = ((const float4v*)emb)[i];
    u16x4 o;
    o.x = f2bf(v.x); o.y = f2bf(v.y); o.z = f2bf(v.z); o.w = f2bf(v.w);
    ((u16x4*)embbf)[i] = o;
  } else if (blk < 16512) {                            // W1: K=512 N=4096
    const int r = blk - 16000;                         // 64 x 8
    transpose_tile64(W1, W1t, 512, 4096, r & 63, r >> 6, tid);
  } else if (blk < 19584) {                            // W2[i]: K=1024 N=3072
    const int r = blk - 16512;
    const int i = r / 768, rr = r - i * 768;           // 48 x 16 per layer
    transpose_tile64(W2 + (size_t)i * 3145728, W2t + (size_t)i * 3145728,
                     1024, 3072, rr % 48, rr / 48, tid);
  } else {                                             // W3: K=1024 N=2048
    const int r = blk - 19584;                         // 32 x 16
    transpose_tile64(W3, W3t, 1024, 2048, r & 31, r >> 5, tid);
  }
}

extern "C" void kernel_launch(void* const* d_in, const int* in_sizes, int n_in,
                              void* d_out, int out_size, void* d_ws, size_t ws_size,
                              hipStream_t stream) {
  (void)in_sizes; (void)n_in; (void)out_size; (void)ws_size;
  const int*   x     = (const int*)d_in[0];
  const float* c1    = (const float*)d_in[1];
  const float* c2    = (const float*)d_in[2];
  const float* c3    = (const float*)d_in[3];
  const float* emb   = (const float*)d_in[4];
  const float* obias = (const float*)d_in[5];
  const float* W1    = (const float*)d_in[6];
  const float* b1    = (const float*)d_in[7];
  const float* W2    = (const float*)d_in[8];
  const float* b2    = (const float*)d_in[9];
  const float* W3    = (const float*)d_in[10];
  const float* b3    = (const float*)d_in[11];

  char* ws = (char*)d_ws;
  unsigned short* hbfA  = (unsigned short*)ws;                  //  8,388,608 B
  unsigned short* hbfB  = (unsigned short*)(ws + 8388608);      //  8,388,608 B
  unsigned short* embbf = (unsigned short*)(ws + 16777216);     // 32,768,000 B
  unsigned short* W1t   = (unsigned short*)(ws + 49545216);     //  4,194,304 B
  unsigned short* W2t   = (unsigned short*)(ws + 53739520);     // 25,165,824 B
  unsigned short* W3t   = (unsigned short*)(ws + 78905344);     //  4,194,304 B
  unsigned short* U = (unsigned short*)d_out;  // bf16 U scratch (<=34MB) in
                                               // d_out; logits overwrite it.

  // input prep in one launch (emb cvt + 6 transposes — independent)
  prep_k<<<20096, 256, 0, stream>>>(emb, W1, W2, W3, embbf, W1t, W2t, W3t);

  // ---- layer 1: (512 -> 1024, k=4): 32x32 = 1024 tiles, A = gather(embbf,x)
  gemm128<true, true><<<1024, 256, 0, stream>>>(embbf, W1t, U, nullptr, x,
                                                4096, 4096, 512, 32);
  scan_k<true><<<512, 64, 0, stream>>>(U, b1, c1, hbfB, hbfB, 1024);

  // ---- mid layers: 4x (1024 -> 1024, k=3): 32x24 = 768 tiles ----
  const unsigned short* hin = hbfB;
  unsigned short* hout = hbfA;
  for (int i = 0; i < 4; ++i) {
    gemm128<true, false><<<768, 256, 0, stream>>>(hin, W2t + (size_t)i * 3145728,
                                                  U, nullptr, nullptr,
                                                  4096, 3072, 1024, 32);
    scan_k<false><<<512, 64, 0, stream>>>(U, b2 + i * 2048, c2 + (size_t)i * 32768,
                                          hin, hout, 1024);
    const unsigned short* t = hin; hin = hout; hout = (unsigned short*)t;
  }

  // ---- final SRU: (1024 -> 512, k=4): 32x16 = 512 tiles ----
  gemm128<true, false><<<512, 256, 0, stream>>>(hin, W3t, U, nullptr, nullptr,
                                                4096, 2048, 1024, 32);
  scan_k<true><<<256, 64, 0, stream>>>(U, b3, c3, hout, hout, 512);

  // ---- logits: (4096 x 32000): 32x250 = 8000 tiles, fp32 + bias ----
  gemm128<false, false><<<8000, 256, 0, stream>>>(hout, embbf, (float*)d_out,
                                                  obias, nullptr,
                                                  4096, 32000, 512, 32);
}

// Round 13
// 544.324 us; speedup vs baseline: 1.5918x; 1.1244x over previous
//
#include <hip/hip_runtime.h>

// ---------------------------------------------------------------------------
// SRU LM: emb-gather -> SRU(512->1024,k4) -> 4x SRU(1024,k3) -> SRU(1024->512,k4)
//         -> logits = h @ emb^T + bias
// L=128 B=32 E=512 D=1024 V=32000 MID=4
// Round 13 = round 12 (612us) + NON-TEMPORAL stores for the logits fp32 C
// epilogue: C (524MB, write-once) no longer allocates in L2/L3, so the
// embbf B panels (32MB, re-read by all 32 m-panel groups) stay cache-
// resident (round-7 evidence: logits FETCH 284MB >> 36MB logical A+B).
// GEMM: 128x128 tile (m97 structure), 16x16x32 MFMA, 256 thr, single-buffered
// 32KiB LDS, ~4 blocks/CU; XCD-bijective swizzle, m-fastest tile order;
// write-combined epilogue; L1 A-operand = fused token gather.
// Scans: 4-deep pipelined, bf16 U.  U bf16 scratch in d_out.
// ---------------------------------------------------------------------------

typedef __attribute__((ext_vector_type(8))) __bf16 bf16x8;
typedef __attribute__((ext_vector_type(4))) float f32x4;
typedef __attribute__((ext_vector_type(4))) float float4v;
typedef __attribute__((ext_vector_type(4))) unsigned short u16x4;

__device__ __forceinline__ unsigned short f2bf(float f) {
  unsigned int u = __builtin_bit_cast(unsigned int, f);
  u += 0x7fffu + ((u >> 16) & 1u);          // RNE
  return (unsigned short)(u >> 16);
}
__device__ __forceinline__ float bf2f(unsigned short v) {
  unsigned int u = ((unsigned int)v) << 16;
  return __builtin_bit_cast(float, u);
}

#define GLDS16(SRC, DST)                                                      \
  __builtin_amdgcn_global_load_lds(                                           \
      (__attribute__((address_space(1))) void*)(SRC),                         \
      (__attribute__((address_space(3))) void*)(DST), 16, 0, 0)

// ---------------------------------------------------------------------------
// 128x128-tile GEMM (m97 structure).  C[m][n] = sum_k A[m][k]*B[n][k].
// A:(M,K) bf16, B:(N,K) bf16.  BF16OUT: C bf16 (no bias) else C fp32 (+bias,
// non-temporal stores — logits-only path).
// GATHER: A-row r sourced from A + x[m0+r]*K (token gather; A=embbf, K=512).
// M%128==0, N%128==0, K%64==0, grid%8==0.  256 thr = 4 waves (2x2),
// 64x64 out/wave (4x4 frags).  Single-buffered BK=64.
// LDS slot-swizzle: LDS[row][slot] = global 16B-slot (slot ^ (row&7)).
// Tile order m-fastest: consecutive wg on an XCD share B n-panel (L2).
// ---------------------------------------------------------------------------
template <bool BF16OUT, bool GATHER>
__global__ __launch_bounds__(256, 4)
void gemm128(const unsigned short* __restrict__ A,
             const unsigned short* __restrict__ B,
             void* __restrict__ Cv, const float* __restrict__ bias,
             const int* __restrict__ xrow,
             int M, int N, int K, int tiles_m) {
  __shared__ __align__(16) unsigned short As[128 * 64];
  __shared__ __align__(16) unsigned short Bs[128 * 64];
  __shared__ int xs[128];

  const int tid  = threadIdx.x;
  const int lane = tid & 63;
  const int wave = tid >> 6;
  const int wm = wave >> 1, wn = wave & 1;

  // bijective XCD swizzle (nwg % 8 == 0 for all our grids)
  const int nwg  = gridDim.x;
  const int orig = blockIdx.x;
  const int wg   = (orig & 7) * (nwg >> 3) + (orig >> 3);
  const int by = wg % tiles_m, bx = wg / tiles_m;   // m-fastest
  const int m0 = by * 128, n0 = bx * 128;

  if constexpr (GATHER) {
    if (tid < 128) xs[tid] = xrow[m0 + tid];
    __syncthreads();
  }

  const int srow  = lane >> 3;
  const int sslot = (lane & 7) ^ srow;
  const int fr = lane & 15;
  const int s0 = (lane >> 4) ^ (lane & 7);
  const int lg = lane >> 4;

  f32x4 acc[4][4] = {};

  const int ksteps = K >> 6;
  for (int ks = 0; ks < ksteps; ++ks) {
    const int k0 = ks << 6;
#pragma unroll
    for (int j = 0; j < 4; ++j) {
      const int rbase = (j * 4 + wave) * 8;          // wave-uniform
      const int r = rbase + srow;
      const unsigned short* sa;
      if constexpr (GATHER)
        sa = A + (size_t)xs[r] * K + k0 + sslot * 8;
      else
        sa = A + (size_t)(m0 + r) * K + k0 + sslot * 8;
      const unsigned short* sb = B + (size_t)(n0 + r) * K + k0 + sslot * 8;
      GLDS16(sa, &As[rbase * 64]);
      GLDS16(sb, &Bs[rbase * 64]);
    }
    __syncthreads();
#pragma unroll
    for (int kk = 0; kk < 2; ++kk) {
      const int slot = s0 ^ (kk << 2);
      bf16x8 a[4], b[4];
#pragma unroll
      for (int m = 0; m < 4; ++m)
        a[m] = *(const bf16x8*)&As[(wm * 64 + m * 16 + fr) * 64 + slot * 8];
#pragma unroll
      for (int n = 0; n < 4; ++n)
        b[n] = *(const bf16x8*)&Bs[(wn * 64 + n * 16 + fr) * 64 + slot * 8];
#pragma unroll
      for (int m = 0; m < 4; ++m)
#pragma unroll
        for (int n = 0; n < 4; ++n)
          acc[m][n] = __builtin_amdgcn_mfma_f32_16x16x32_bf16(a[m], b[n],
                                                              acc[m][n], 0, 0, 0);
    }
    __syncthreads();
  }

  // epilogue, write-combined order (m,r outer / n inner — round-8 lesson):
  // fp32: 4 x 64B segments/row back-to-back; bf16: 4 x 32B segs = 128B line.
  if constexpr (BF16OUT) {
    unsigned short* C = (unsigned short*)Cv;
#pragma unroll
    for (int m = 0; m < 4; ++m) {
      const int row = m0 + wm * 64 + m * 16 + lg * 4;
#pragma unroll
      for (int r = 0; r < 4; ++r) {
        unsigned short* Crow = C + (size_t)(row + r) * N + n0 + wn * 64 + fr;
#pragma unroll
        for (int n = 0; n < 4; ++n)
          Crow[n * 16] = f2bf(acc[m][n][r]);
      }
    }
  } else {
    // fp32 path = logits only.  Non-temporal: C is write-once, never re-read
    // in-kernel; keep L2/L3 for the B panels instead of 524MB of C lines.
    float* C = (float*)Cv;
    float bv[4];
#pragma unroll
    for (int n = 0; n < 4; ++n)
      bv[n] = bias ? bias[n0 + wn * 64 + n * 16 + fr] : 0.0f;
#pragma unroll
    for (int m = 0; m < 4; ++m) {
      const int row = m0 + wm * 64 + m * 16 + lg * 4;
#pragma unroll
      for (int r = 0; r < 4; ++r) {
        float* Crow = C + (size_t)(row + r) * N + n0 + wn * 64 + fr;
#pragma unroll
        for (int n = 0; n < 4; ++n)
          __builtin_nontemporal_store(acc[m][n][r] + bv[n], &Crow[n * 16]);
      }
    }
  }
}

// ---------------------------------------------------------------------------
// SRU scan, 4-deep software-pipelined.  One thread per (b,d) chain, L=128.
// U is bf16 (L,B,k*n_out).  hw = U[...,3n:] if K4 else bf16 hin.
// ---------------------------------------------------------------------------
template <bool K4>
__global__ void scan_k(const unsigned short* __restrict__ U,
                       const float* __restrict__ bias,
                       const float* __restrict__ c0,
                       const unsigned short* __restrict__ hin,
                       unsigned short* __restrict__ hout, int n_out) {
  const int idx = blockIdx.x * 64 + threadIdx.x;     // 0 .. 32*n_out
  const int b = idx / n_out;
  const int d = idx - b * n_out;
  const float biasf = bias[d];
  const float biasr = bias[n_out + d];
  float c = c0[idx];
  const int rowlen = (K4 ? 4 : 3) * n_out;
  const unsigned short* Up = U + (size_t)b * rowlen + d;
  const size_t lstride = (size_t)32 * rowlen;
  const unsigned short* hp = hin + (size_t)b * n_out + d;
  unsigned short* op = hout + (size_t)b * n_out + d;
  const size_t hstride = (size_t)32 * n_out;

  float xt0, fr0, rr0, hw0, xt1, fr1, rr1, hw1;
  float xt2, fr2, rr2, hw2, xt3, fr3, rr3, hw3;

#define SRU_LOAD(S)                                                           \
  do {                                                                        \
    xt##S = bf2f(Up[0]);                                                      \
    fr##S = bf2f(Up[n_out]);                                                  \
    rr##S = bf2f(Up[2 * n_out]);                                              \
    hw##S = K4 ? bf2f(Up[3 * n_out]) : bf2f(*hp);                             \
    Up += lstride;                                                            \
    hp += hstride;                                                            \
  } while (0)

#define SRU_STEP(S)                                                           \
  do {                                                                        \
    const float f = 1.0f / (1.0f + __expf(-(fr##S + biasf)));                 \
    const float r = 1.0f / (1.0f + __expf(-(rr##S + biasr)));                 \
    c = f * c + (1.0f - f) * xt##S;                                           \
    const float e2 = __expf(2.0f * c);                                        \
    const float g = 1.0f - 2.0f / (e2 + 1.0f);                                \
    *op = f2bf(r * g + (1.0f - r) * hw##S);                                   \
    op += hstride;                                                            \
  } while (0)

  SRU_LOAD(0); SRU_LOAD(1); SRU_LOAD(2); SRU_LOAD(3);   // l = 0..3
  for (int l = 0; l < 124; l += 4) {                    // l = 0,4,...,120
    SRU_STEP(0); SRU_LOAD(0);                           // load l+4
    SRU_STEP(1); SRU_LOAD(1);
    SRU_STEP(2); SRU_LOAD(2);
    SRU_STEP(3); SRU_LOAD(3);
  }
  SRU_STEP(0); SRU_STEP(1); SRU_STEP(2); SRU_STEP(3);   // l = 124..127
#undef SRU_LOAD
#undef SRU_STEP
}

// ---------------------------------------------------------------------------
// Fused prep: emb->bf16 cvt + all 6 weight transposes (64x64 tiles ->
// 128B-per-instruction output rows).  256 thr/block.
// ---------------------------------------------------------------------------
__device__ __forceinline__ void transpose_tile64(const float* __restrict__ W,
                                                 unsigned short* __restrict__ Wt,
                                                 int K, int N, int bx, int by,
                                                 int tid) {
  __shared__ float tile[64][65];
  const int n0 = bx * 64, k0 = by * 64;
  const int tx = tid & 63, ty = tid >> 6;   // (64,4)
#pragma unroll
  for (int i = 0; i < 64; i += 4)
    tile[ty + i][tx] = W[(size_t)(k0 + ty + i) * N + n0 + tx];
  __syncthreads();
#pragma unroll
  for (int i = 0; i < 64; i += 4)
    Wt[(size_t)(n0 + ty + i) * K + k0 + tx] = f2bf(tile[tx][ty + i]);
}

__global__ void prep_k(const float* __restrict__ emb,
                       const float* __restrict__ W1,
                       const float* __restrict__ W2,
                       const float* __restrict__ W3,
                       unsigned short* __restrict__ embbf,
                       unsigned short* __restrict__ W1t,
                       unsigned short* __restrict__ W2t,
                       unsigned short* __restrict__ W3t) {
  const int blk = blockIdx.x;
  const int tid = threadIdx.x;
  if (blk < 16000) {                                   // cvt emb -> bf16
    const int i = blk * 256 + tid;
    const float4v v = ((const float4v*)emb)[i];
    u16x4 o;
    o.x = f2bf(v.x); o.y = f2bf(v.y); o.z = f2bf(v.z); o.w = f2bf(v.w);
    ((u16x4*)embbf)[i] = o;
  } else if (blk < 16512) {                            // W1: K=512 N=4096
    const int r = blk - 16000;                         // 64 x 8
    transpose_tile64(W1, W1t, 512, 4096, r & 63, r >> 6, tid);
  } else if (blk < 19584) {                            // W2[i]: K=1024 N=3072
    const int r = blk - 16512;
    const int i = r / 768, rr = r - i * 768;           // 48 x 16 per layer
    transpose_tile64(W2 + (size_t)i * 3145728, W2t + (size_t)i * 3145728,
                     1024, 3072, rr % 48, rr / 48, tid);
  } else {                                             // W3: K=1024 N=2048
    const int r = blk - 19584;                         // 32 x 16
    transpose_tile64(W3, W3t, 1024, 2048, r & 31, r >> 5, tid);
  }
}

extern "C" void kernel_launch(void* const* d_in, const int* in_sizes, int n_in,
                              void* d_out, int out_size, void* d_ws, size_t ws_size,
                              hipStream_t stream) {
  (void)in_sizes; (void)n_in; (void)out_size; (void)ws_size;
  const int*   x     = (const int*)d_in[0];
  const float* c1    = (const float*)d_in[1];
  const float* c2    = (const float*)d_in[2];
  const float* c3    = (const float*)d_in[3];
  const float* emb   = (const float*)d_in[4];
  const float* obias = (const float*)d_in[5];
  const float* W1    = (const float*)d_in[6];
  const float* b1    = (const float*)d_in[7];
  const float* W2    = (const float*)d_in[8];
  const float* b2    = (const float*)d_in[9];
  const float* W3    = (const float*)d_in[10];
  const float* b3    = (const float*)d_in[11];

  char* ws = (char*)d_ws;
  unsigned short* hbfA  = (unsigned short*)ws;                  //  8,388,608 B
  unsigned short* hbfB  = (unsigned short*)(ws + 8388608);      //  8,388,608 B
  unsigned short* embbf = (unsigned short*)(ws + 16777216);     // 32,768,000 B
  unsigned short* W1t   = (unsigned short*)(ws + 49545216);     //  4,194,304 B
  unsigned short* W2t   = (unsigned short*)(ws + 53739520);     // 25,165,824 B
  unsigned short* W3t   = (unsigned short*)(ws + 78905344);     //  4,194,304 B
  unsigned short* U = (unsigned short*)d_out;  // bf16 U scratch (<=34MB) in
                                               // d_out; logits overwrite it.

  // input prep in one launch (emb cvt + 6 transposes — independent)
  prep_k<<<20096, 256, 0, stream>>>(emb, W1, W2, W3, embbf, W1t, W2t, W3t);

  // ---- layer 1: (512 -> 1024, k=4): 32x32 = 1024 tiles, A = gather(embbf,x)
  gemm128<true, true><<<1024, 256, 0, stream>>>(embbf, W1t, U, nullptr, x,
                                                4096, 4096, 512, 32);
  scan_k<true><<<512, 64, 0, stream>>>(U, b1, c1, hbfB, hbfB, 1024);

  // ---- mid layers: 4x (1024 -> 1024, k=3): 32x24 = 768 tiles ----
  const unsigned short* hin = hbfB;
  unsigned short* hout = hbfA;
  for (int i = 0; i < 4; ++i) {
    gemm128<true, false><<<768, 256, 0, stream>>>(hin, W2t + (size_t)i * 3145728,
                                                  U, nullptr, nullptr,
                                                  4096, 3072, 1024, 32);
    scan_k<false><<<512, 64, 0, stream>>>(U, b2 + i * 2048, c2 + (size_t)i * 32768,
                                          hin, hout, 1024);
    const unsigned short* t = hin; hin = hout; hout = (unsigned short*)t;
  }

  // ---- final SRU: (1024 -> 512, k=4): 32x16 = 512 tiles ----
  gemm128<true, false><<<512, 256, 0, stream>>>(hin, W3t, U, nullptr, nullptr,
                                                4096, 2048, 1024, 32);
  scan_k<true><<<256, 64, 0, stream>>>(U, b3, c3, hout, hout, 512);

  // ---- logits: (4096 x 32000): 32x250 = 8000 tiles, fp32 + bias, NT-C ----
  gemm128<false, false><<<8000, 256, 0, stream>>>(hout, embbf, (float*)d_out,
                                                  obias, nullptr,
                                                  4096, 32000, 512, 32);
}